// Round 1
// baseline (4522.568 us; speedup 1.0000x reference)
//
#include <hip/hip_runtime.h>
#include <math.h>

// ---------------------------------------------------------------------------
// Fused 9-layer MLP decoder, fp32 baseline (round 1: correctness + VALU roofline).
//   dims: 2 -> 100 -> 100 -> 100 -> 98 -> [concat input -> 100] -> 100 -> 100 -> 100 -> 1
//   softplus(beta=100) after layers 0..7.
// One thread per row. Activations live in a per-thread LDS slice (stride 101
// floats -> 2-way bank aliasing only, which is free). Accumulators y[100] in
// VGPRs with static j-indexing; dynamic i-loop keeps code size bounded.
// Weights are pre-transposed to [in][out] in d_ws so the inner loop reads a
// contiguous, wave-uniform weight row (scalar-load friendly).
// ---------------------------------------------------------------------------

#define TPB 128
#define XSTRIDE 101

__device__ __forceinline__ float sp100(float x) {
    // Softplus(beta=100): (1/100)*log1p(exp(100x)), linear above 100x > 20
    float bx = 100.0f * x;
    float e  = __expf(bx);            // hw exp, ~2^-21 rel err; inf for big bx is fine (discarded)
    float s  = 0.01f * log1pf(e);
    return (bx > 20.0f) ? x : s;
}

template<int IN, int OUT>
__device__ __forceinline__ void dense_layer(const float* __restrict__ wt,   // [IN][OUT] transposed
                                            const float* __restrict__ bias, // [OUT]
                                            float* __restrict__ xp)         // LDS slice, len >= max(IN,OUT)
{
    float y[OUT];
#pragma unroll
    for (int j = 0; j < OUT; ++j) y[j] = bias[j];

#pragma unroll 2
    for (int i = 0; i < IN; ++i) {
        const float xi = xp[i];
        const float* __restrict__ wr = wt + i * OUT;
#pragma unroll
        for (int j = 0; j < OUT; ++j) y[j] = fmaf(wr[j], xi, y[j]);
    }

#pragma unroll
    for (int j = 0; j < OUT; ++j) xp[j] = sp100(y[j]);
}

__global__ __launch_bounds__(TPB, 1) void mlp_fwd(
    const float* __restrict__ inp, const float* __restrict__ wt,
    const float* __restrict__ b0, const float* __restrict__ b1, const float* __restrict__ b2,
    const float* __restrict__ b3, const float* __restrict__ b4, const float* __restrict__ b5,
    const float* __restrict__ b6, const float* __restrict__ b7, const float* __restrict__ b8,
    float* __restrict__ out)
{
    __shared__ float xs[TPB * XSTRIDE];
    const int tid = threadIdx.x;
    const int row = blockIdx.x * TPB + tid;
    float* xp = &xs[tid * XSTRIDE];

    const float2 in2 = *reinterpret_cast<const float2*>(inp + (size_t)row * 2);
    const float in0 = in2.x, in1 = in2.y;

    // L0: [2 -> 100]
    {
        const float* __restrict__ w = wt;  // [2][100]
#pragma unroll
        for (int j = 0; j < 100; ++j) {
            float v = fmaf(w[j], in0, fmaf(w[100 + j], in1, b0[j]));
            xp[j] = sp100(v);
        }
    }

    dense_layer<100, 100>(wt + 200,   b1, xp);   // L1
    dense_layer<100, 100>(wt + 10200, b2, xp);   // L2
    dense_layer<100,  98>(wt + 20200, b3, xp);   // L3 -> xp[0..97]

    // skip concat: x_cat = [in0, in1, x3[0..97]]
#pragma unroll
    for (int j = 97; j >= 0; --j) xp[j + 2] = xp[j];
    xp[0] = in0;
    xp[1] = in1;

    dense_layer<100, 100>(wt + 30000, b4, xp);   // L4
    dense_layer<100, 100>(wt + 40000, b5, xp);   // L5
    dense_layer<100, 100>(wt + 50000, b6, xp);   // L6
    dense_layer<100, 100>(wt + 60000, b7, xp);   // L7

    // L8: [100 -> 1], no activation
    {
        const float* __restrict__ w = wt + 70000;
        float a0 = b8[0], a1 = 0.0f, a2 = 0.0f, a3 = 0.0f;
#pragma unroll 1
        for (int i = 0; i < 100; i += 4) {
            a0 = fmaf(w[i + 0], xp[i + 0], a0);
            a1 = fmaf(w[i + 1], xp[i + 1], a1);
            a2 = fmaf(w[i + 2], xp[i + 2], a2);
            a3 = fmaf(w[i + 3], xp[i + 3], a3);
        }
        out[row] = (a0 + a1) + (a2 + a3);
    }
}

// Transpose torch-convention W [out][in] -> WT [in][out] into d_ws.
// Offsets (floats): L0:0(200) L1:200 L2:10200 L3:20200 L4:30000 L5:40000
//                   L6:50000 L7:60000 L8:70000  (total 70100 floats = 280,400 B)
__global__ void transpose_weights(
    const float* __restrict__ W0, const float* __restrict__ W1, const float* __restrict__ W2,
    const float* __restrict__ W3, const float* __restrict__ W4, const float* __restrict__ W5,
    const float* __restrict__ W6, const float* __restrict__ W7, const float* __restrict__ W8,
    float* __restrict__ wt)
{
    const float* W; int IN, OUT, off;
    switch (blockIdx.x) {
    case 0:  W = W0; IN = 2;   OUT = 100; off = 0;     break;
    case 1:  W = W1; IN = 100; OUT = 100; off = 200;   break;
    case 2:  W = W2; IN = 100; OUT = 100; off = 10200; break;
    case 3:  W = W3; IN = 100; OUT = 98;  off = 20200; break;
    case 4:  W = W4; IN = 100; OUT = 100; off = 30000; break;
    case 5:  W = W5; IN = 100; OUT = 100; off = 40000; break;
    case 6:  W = W6; IN = 100; OUT = 100; off = 50000; break;
    case 7:  W = W7; IN = 100; OUT = 100; off = 60000; break;
    default: W = W8; IN = 100; OUT = 1;   off = 70000; break;
    }
    const int n = IN * OUT;
    for (int idx = threadIdx.x; idx < n; idx += blockDim.x) {
        int j = idx / IN;          // out index
        int i = idx - j * IN;      // in index
        wt[off + i * OUT + j] = W[idx];
    }
}

extern "C" void kernel_launch(void* const* d_in, const int* in_sizes, int n_in,
                              void* d_out, int out_size, void* d_ws, size_t ws_size,
                              hipStream_t stream)
{
    const float* inp = (const float*)d_in[0];
    const float* W[9];
    const float* B[9];
    for (int l = 0; l < 9; ++l) {
        W[l] = (const float*)d_in[1 + 2 * l];
        B[l] = (const float*)d_in[2 + 2 * l];
    }
    float* wt  = (float*)d_ws;          // needs 280,400 B of workspace
    float* out = (float*)d_out;
    const int N = in_sizes[0] / 2;      // 1,048,576 rows

    transpose_weights<<<9, 256, 0, stream>>>(W[0], W[1], W[2], W[3], W[4],
                                             W[5], W[6], W[7], W[8], wt);
    mlp_fwd<<<N / TPB, TPB, 0, stream>>>(inp, wt,
                                         B[0], B[1], B[2], B[3], B[4],
                                         B[5], B[6], B[7], B[8], out);
}

// Round 5
// 1559.875 us; speedup vs baseline: 2.8993x; 2.8993x over previous
//
#include <hip/hip_runtime.h>
#include <math.h>

// Round 3/4: 3-term split-fp16 MFMA (fp32-quality):
//   X = Xh + Xl, W = Wh + Wl (fp16 hi/lo), acc = Xh*Wh + Xl*Wh + Xh*Wl.
// 512 thr / 8 waves / 128 rows per block. Waves = 4 row-groups x 2 col-groups.
// XT: fp32 [128][128] in LDS, XOR-swizzled ((row&7)<<5); hi/lo fp16 derived
// in regs at A-read. W: hi+lo fp16 frag-major in LDS (56 KB), staged per
// layer via issue-early/write-late reg path (T14).

typedef _Float16 half8 __attribute__((ext_vector_type(8)));
typedef float f32x4 __attribute__((ext_vector_type(4)));

#define TPB 512
#define RPB 128

__device__ __forceinline__ float sp100(float x) {
    // softplus(100x)/100 = max(x,0) + ln2/100 * log2(1 + 2^(-(100/ln2)*|x|))
    float t = exp2f(-144.26950408889634f * fabsf(x));
    return fmaxf(x, 0.0f) + 0.0069314718055994531f * log2f(1.0f + t);
}

// byte offset of fp32 XT[row][k], row stride 512 B, 32B-slot XOR swizzle
__device__ __forceinline__ int xtb(int row, int k) {
    return ((row << 9) + (k << 2)) ^ ((row & 7) << 5);
}

template<int NT, int TB>
__device__ __forceinline__ void mfma_phase(f32x4 (&acc)[2][NT],
        const float* XT, const uint4* Wb, int lane, int rg)
{
#pragma unroll
    for (int s = 0; s < 4; ++s) {
        half8 Ah[2], Al[2];
#pragma unroll
        for (int rt = 0; rt < 2; ++rt) {
            int row = rg * 32 + rt * 16 + (lane & 15);
            int k0  = s * 32 + (lane >> 4) * 8;
            f32x4 x0 = *reinterpret_cast<const f32x4*>(
                           reinterpret_cast<const char*>(XT) + xtb(row, k0));
            f32x4 x1 = *reinterpret_cast<const f32x4*>(
                           reinterpret_cast<const char*>(XT) + xtb(row, k0 + 4));
            float xf[8] = {x0[0], x0[1], x0[2], x0[3], x1[0], x1[1], x1[2], x1[3]};
#pragma unroll
            for (int j = 0; j < 8; ++j) {
                _Float16 h = (_Float16)xf[j];
                Ah[rt][j] = h;
                Al[rt][j] = (_Float16)(xf[j] - (float)h);
            }
        }
#pragma unroll
        for (int tt = 0; tt < NT; ++tt) {
            int st = s * 7 + TB + tt;
            half8 Bh = *reinterpret_cast<const half8*>(&Wb[st * 64 + lane]);
            half8 Bl = *reinterpret_cast<const half8*>(&Wb[1792 + st * 64 + lane]);
#pragma unroll
            for (int rt = 0; rt < 2; ++rt) {
                acc[rt][tt] = __builtin_amdgcn_mfma_f32_16x16x32_f16(Ah[rt], Bh, acc[rt][tt], 0, 0, 0);
                acc[rt][tt] = __builtin_amdgcn_mfma_f32_16x16x32_f16(Al[rt], Bh, acc[rt][tt], 0, 0, 0);
                acc[rt][tt] = __builtin_amdgcn_mfma_f32_16x16x32_f16(Ah[rt], Bl, acc[rt][tt], 0, 0, 0);
            }
        }
    }
}

template<int NT, int TB>
__device__ __forceinline__ void epilogue_mid(f32x4 (&acc)[2][NT],
        const float* __restrict__ bias, int Nl, int cshift,
        float* XT, int lane, int rg)
{
#pragma unroll
    for (int tt = 0; tt < NT; ++tt) {
        int n = (TB + tt) * 16 + (lane & 15);
        float bv = (n < Nl) ? bias[n] : 0.0f;
#pragma unroll
        for (int rt = 0; rt < 2; ++rt) {
#pragma unroll
            for (int i = 0; i < 4; ++i) {
                float y = sp100(acc[rt][tt][i] + bv);
                int row = rg * 32 + rt * 16 + (lane >> 4) * 4 + i;
                *reinterpret_cast<float*>(
                    reinterpret_cast<char*>(XT) + xtb(row, n + cshift)) = y;
            }
        }
    }
}

__global__ __launch_bounds__(TPB, 2) void mlp_fwd(
    const float* __restrict__ inp,
    const uint4* __restrict__ wpk,   // 7 layers x 3584 uint4: [term][s*7+t][lane]
    const float* __restrict__ W0, const float* __restrict__ b0,
    const float* __restrict__ b1, const float* __restrict__ b2,
    const float* __restrict__ b3, const float* __restrict__ b4,
    const float* __restrict__ b5, const float* __restrict__ b6,
    const float* __restrict__ b7,
    const float* __restrict__ W8, const float* __restrict__ b8,
    float* __restrict__ out)
{
    __shared__ float XT[RPB * 128];    // 64 KB fp32 activations, swizzled
    __shared__ uint4 Wb[3584];         // 56 KB current layer Wh+Wl frags
    __shared__ float inps[RPB * 2];
    __shared__ float w0s[304];
    __shared__ float part[2][RPB];

    const int tid  = threadIdx.x;
    const int lane = tid & 63;
    const int wid  = tid >> 6;
    const int rg   = wid & 3;          // row-group: rows 32rg..32rg+31
    const int cg   = wid >> 2;         // col-group: 0 -> tiles 0..3, 1 -> 4..6
    const int bid  = blockIdx.x;

    // stage inputs + W0/b0; prefetch layer-1 packed weights
    if (tid < 128) {
        float2 v = *reinterpret_cast<const float2*>(inp + ((size_t)bid * RPB + tid) * 2);
        inps[tid * 2]     = v.x;
        inps[tid * 2 + 1] = v.y;
    } else if (tid < 428) {
        int q = tid - 128;
        w0s[q] = (q < 200) ? W0[q] : b0[q - 200];
    }

    uint4 wv[7];
#pragma unroll
    for (int r = 0; r < 7; ++r) wv[r] = wpk[r * TPB + tid];   // layer 1

    __syncthreads();

    // L0: [2 -> 100] in fp32 VALU; zero-fills k pad (cols 100..127)
#pragma unroll
    for (int it = 0; it < 4; ++it) {
        int task = it * TPB + tid;            // 0..2047
        int row  = task >> 4;
        int c0   = (task & 15) << 3;          // 0,8,...,120
        float i0 = inps[row * 2], i1 = inps[row * 2 + 1];
        f32x4 y0, y1;
#pragma unroll
        for (int p = 0; p < 8; ++p) {
            int c = c0 + p;
            float y = 0.0f;
            if (c < 100)
                y = sp100(fmaf(i0, w0s[c * 2], fmaf(i1, w0s[c * 2 + 1], w0s[200 + c])));
            if (p < 4) y0[p] = y; else y1[p - 4] = y;
        }
        *reinterpret_cast<f32x4*>(reinterpret_cast<char*>(XT) + xtb(row, c0))     = y0;
        *reinterpret_cast<f32x4*>(reinterpret_cast<char*>(XT) + xtb(row, c0 + 4)) = y1;
    }
    // commit layer-1 weights
#pragma unroll
    for (int r = 0; r < 7; ++r) Wb[r * TPB + tid] = wv[r];
    __syncthreads();

    // layers 1..6
#pragma unroll 1
    for (int l = 1; l <= 6; ++l) {
        const float* bp = (l == 1) ? b1 : (l == 2) ? b2 : (l == 3) ? b3 :
                          (l == 4) ? b4 : (l == 5) ? b5 : b6;
        f32x4 acc0[2][4];
        f32x4 acc1[2][3];
        if (cg == 0) {
#pragma unroll
            for (int a = 0; a < 2; ++a)
#pragma unroll
                for (int t = 0; t < 4; ++t) acc0[a][t] = f32x4{0.f, 0.f, 0.f, 0.f};
            mfma_phase<4, 0>(acc0, XT, Wb, lane, rg);
        } else {
#pragma unroll
            for (int a = 0; a < 2; ++a)
#pragma unroll
                for (int t = 0; t < 3; ++t) acc1[a][t] = f32x4{0.f, 0.f, 0.f, 0.f};
            mfma_phase<3, 4>(acc1, XT, Wb, lane, rg);
        }
        __syncthreads();   // all XT / Wb reads of layer l complete

        // issue next layer's packed-weight loads (complete under epilogue VALU)
#pragma unroll
        for (int r = 0; r < 7; ++r) wv[r] = wpk[l * 3584 + r * TPB + tid];

        const int Nl = (l == 3) ? 98 : 100;
        const int cs = (l == 3) ? 2 : 0;
        if (cg == 0) epilogue_mid<4, 0>(acc0, bp, Nl, cs, XT, lane, rg);
        else         epilogue_mid<3, 4>(acc1, bp, Nl, cs, XT, lane, rg);

        if (l == 3 && tid < 256) {   // skip-concat: raw inputs -> cols 0,1
            int row = tid >> 1, c = tid & 1;
            *reinterpret_cast<float*>(
                reinterpret_cast<char*>(XT) + xtb(row, c)) = inps[row * 2 + c];
        }
        // commit next layer's weights
#pragma unroll
        for (int r = 0; r < 7; ++r) Wb[r * TPB + tid] = wv[r];
        __syncthreads();
    }

    // layer 7 + fused L8 dot
    {
        f32x4 acc0[2][4];
        f32x4 acc1[2][3];
        float p8[2][4] = {{0.f, 0.f, 0.f, 0.f}, {0.f, 0.f, 0.f, 0.f}};
        if (cg == 0) {
#pragma unroll
            for (int a = 0; a < 2; ++a)
#pragma unroll
                for (int t = 0; t < 4; ++t) acc0[a][t] = f32x4{0.f, 0.f, 0.f, 0.f};
            mfma_phase<4, 0>(acc0, XT, Wb, lane, rg);
#pragma unroll
            for (int tt = 0; tt < 4; ++tt) {
                int n = tt * 16 + (lane & 15);
                float bv = b7[n];
                float w8 = W8[n];
#pragma unroll
                for (int rt = 0; rt < 2; ++rt)
#pragma unroll
                    for (int i = 0; i < 4; ++i)
                        p8[rt][i] = fmaf(w8, sp100(acc0[rt][tt][i] + bv), p8[rt][i]);
            }
        } else {
#pragma unroll
            for (int a = 0; a < 2; ++a)
#pragma unroll
                for (int t = 0; t < 3; ++t) acc1[a][t] = f32x4{0.f, 0.f, 0.f, 0.f};
            mfma_phase<3, 4>(acc1, XT, Wb, lane, rg);
#pragma unroll
            for (int tt = 0; tt < 3; ++tt) {
                int n = (4 + tt) * 16 + (lane & 15);
                float bv = (n < 100) ? b7[n] : 0.0f;
                float w8 = (n < 100) ? W8[n] : 0.0f;
#pragma unroll
                for (int rt = 0; rt < 2; ++rt)
#pragma unroll
                    for (int i = 0; i < 4; ++i)
                        p8[rt][i] = fmaf(w8, sp100(acc1[rt][tt][i] + bv), p8[rt][i]);
            }
        }
        // reduce 16 col-lanes -> row partial, store per col-group
#pragma unroll
        for (int rt = 0; rt < 2; ++rt)
#pragma unroll
            for (int i = 0; i < 4; ++i) {
                float v = p8[rt][i];
                v += __shfl_xor(v, 1);
                v += __shfl_xor(v, 2);
                v += __shfl_xor(v, 4);
                v += __shfl_xor(v, 8);
                if ((lane & 15) == 0)
                    part[cg][rg * 32 + rt * 16 + (lane >> 4) * 4 + i] = v;
            }
        __syncthreads();
        if (tid < 128)
            out[(size_t)bid * RPB + tid] = part[0][tid] + part[1][tid] + b8[0];
    }
}

// Pack W1..W7 ([out][in=100] fp32) -> per-layer [term(h/l)][s*7+t][lane] half8.
// half jj of entry: value at k=32s+8*(lane>>4)+jj, n=16t+(lane&15);
// term0 = (f16)W, term1 = (f16)(W - (float)(f16)W). Zero outside K=100 / N=Nl.
__global__ void pack_weights(
    const float* __restrict__ W1, const float* __restrict__ W2,
    const float* __restrict__ W3, const float* __restrict__ W4,
    const float* __restrict__ W5, const float* __restrict__ W6,
    const float* __restrict__ W7, uint4* __restrict__ wpk)
{
    const float* Wt[7] = {W1, W2, W3, W4, W5, W6, W7};
    const float* W = Wt[blockIdx.x];
    const int Nl = (blockIdx.x == 2) ? 98 : 100;   // layer 3 outputs 98
    for (int e = threadIdx.x; e < 3584; e += 256) {
        int term = e / 1792;
        int r    = e - term * 1792;
        int lane = r & 63;
        int st   = r >> 6;
        int s    = st / 7;
        int t    = st - s * 7;
        union { _Float16 h[8]; uint4 v; } pk;
#pragma unroll
        for (int jj = 0; jj < 8; ++jj) {
            int k = s * 32 + (lane >> 4) * 8 + jj;
            int n = t * 16 + (lane & 15);
            float val = (k < 100 && n < Nl) ? W[n * 100 + k] : 0.0f;
            _Float16 h = (_Float16)val;
            pk.h[jj] = term ? (_Float16)(val - (float)h) : h;
        }
        wpk[blockIdx.x * 3584 + term * 1792 + r] = pk.v;
    }
}

extern "C" void kernel_launch(void* const* d_in, const int* in_sizes, int n_in,
                              void* d_out, int out_size, void* d_ws, size_t ws_size,
                              hipStream_t stream)
{
    const float* inp = (const float*)d_in[0];
    const float* W[9];
    const float* B[9];
    for (int l = 0; l < 9; ++l) {
        W[l] = (const float*)d_in[1 + 2 * l];
        B[l] = (const float*)d_in[2 + 2 * l];
    }
    uint4* wpk = (uint4*)d_ws;             // 7*3584*16 = 401,408 B
    float* out = (float*)d_out;
    const int N = in_sizes[0] / 2;         // 1,048,576 rows

    pack_weights<<<7, 256, 0, stream>>>(W[1], W[2], W[3], W[4], W[5], W[6], W[7], wpk);
    mlp_fwd<<<N / RPB, TPB, 0, stream>>>(inp, wpk,
                                         W[0], B[0],
                                         B[1], B[2], B[3], B[4], B[5], B[6], B[7],
                                         W[8], B[8],
                                         out);
}

// Round 7
// 885.609 us; speedup vs baseline: 5.1067x; 1.7614x over previous
//
#include <hip/hip_runtime.h>
#include <math.h>

// Round 7: split-fp16 3-term MFMA, spill-free uniform structure.
//   X = Xh + Xl, W = Wh + Wl (fp16), acc = Xh*Wh + Xl*Wh + Xh*Wl.
// 256 thr / 4 waves / 64 rows per block. Wave w owns rows 16w..16w+15 x all
// 7 col-tiles -> acc[7] f32x4, identical shape on every wave.
// B-fragments read DIRECTLY from global (packed 400 KB, L2-resident).
// XT: fp32 [64][128] LDS (32 KB), XOR swizzle ((row&7)<<4).
// Round-6 bug fixed: w0s staging now covers all 304 entries with TPB=256
// (was guarded by tid<364 which 256 threads never reach -> garbage biases).

typedef _Float16 half8 __attribute__((ext_vector_type(8)));
typedef float f32x4 __attribute__((ext_vector_type(4)));

#define TPB 256
#define RPB 64

__device__ __forceinline__ float sp100(float x) {
    // softplus(100x)/100 = max(x,0) + ln2/100 * log2(1 + 2^(-(100/ln2)*|x|))
    float t = exp2f(-144.26950408889634f * fabsf(x));
    return fmaxf(x, 0.0f) + 0.0069314718055994531f * log2f(1.0f + t);
}

// byte offset of fp32 XT[row][k]; row stride 512 B; 16B-slot XOR swizzle
__device__ __forceinline__ int xtb(int row, int k) {
    return ((row << 9) + (k << 2)) ^ ((row & 7) << 4);
}

__global__ __launch_bounds__(TPB, 4) void mlp_fwd(
    const float* __restrict__ inp,
    const half8* __restrict__ wph,   // 7 layers x [term][s*7+t][lane] half8
    const float* __restrict__ W0, const float* __restrict__ b0,
    const float* __restrict__ b1, const float* __restrict__ b2,
    const float* __restrict__ b3, const float* __restrict__ b4,
    const float* __restrict__ b5, const float* __restrict__ b6,
    const float* __restrict__ b7,
    const float* __restrict__ W8, const float* __restrict__ b8,
    float* __restrict__ out)
{
    __shared__ float XT[RPB * 128];    // 32 KB fp32 activations, swizzled
    __shared__ float inps[RPB * 2];
    __shared__ float w0s[304];

    const int tid  = threadIdx.x;
    const int lane = tid & 63;
    const int wid  = tid >> 6;         // wave 0..3 -> rows 16w..16w+15
    const int bid  = blockIdx.x;

    if (tid < RPB) {
        float2 v = *reinterpret_cast<const float2*>(inp + ((size_t)bid * RPB + tid) * 2);
        inps[tid * 2]     = v.x;
        inps[tid * 2 + 1] = v.y;
    }
    for (int q = tid; q < 304; q += TPB)
        w0s[q] = (q < 200) ? W0[q] : b0[q - 200];
    __syncthreads();

    // ---- L0: [2 -> 100] fp32 VALU; zero-fills k pad (cols 100..127) ----
#pragma unroll
    for (int it = 0; it < 4; ++it) {
        int task = it * TPB + tid;            // 0..1023 = 64 rows x 16 col-octets
        int row  = task >> 4;
        int c0   = (task & 15) << 3;
        float i0 = inps[row * 2], i1 = inps[row * 2 + 1];
        f32x4 y0, y1;
#pragma unroll
        for (int p = 0; p < 8; ++p) {
            int c = c0 + p;
            float y = 0.0f;
            if (c < 100)
                y = sp100(fmaf(i0, w0s[c * 2], fmaf(i1, w0s[c * 2 + 1], w0s[200 + c])));
            if (p < 4) y0[p] = y; else y1[p - 4] = y;
        }
        *reinterpret_cast<f32x4*>(reinterpret_cast<char*>(XT) + xtb(row, c0))     = y0;
        *reinterpret_cast<f32x4*>(reinterpret_cast<char*>(XT) + xtb(row, c0 + 4)) = y1;
    }
    __syncthreads();

    // ---- layers 1..7 ----
#pragma unroll 1
    for (int l = 1; l <= 7; ++l) {
        const float* bp = (l == 1) ? b1 : (l == 2) ? b2 : (l == 3) ? b3 :
                          (l == 4) ? b4 : (l == 5) ? b5 : (l == 6) ? b6 : b7;
        const half8* __restrict__ wl = wph + (size_t)(l - 1) * 3584;

        f32x4 acc[7];
#pragma unroll
        for (int t = 0; t < 7; ++t) acc[t] = f32x4{0.f, 0.f, 0.f, 0.f};

#pragma unroll
        for (int s = 0; s < 4; ++s) {
            // A fragment: rows 16*wid + (lane&15), k = 32s + 8*(lane>>4)
            int row = wid * 16 + (lane & 15);
            int k0  = s * 32 + (lane >> 4) * 8;
            f32x4 x0 = *reinterpret_cast<const f32x4*>(
                           reinterpret_cast<const char*>(XT) + xtb(row, k0));
            f32x4 x1 = *reinterpret_cast<const f32x4*>(
                           reinterpret_cast<const char*>(XT) + xtb(row, k0 + 4));
            half8 Ah, Al;
#pragma unroll
            for (int j = 0; j < 4; ++j) {
                _Float16 h0 = (_Float16)x0[j];
                _Float16 h1 = (_Float16)x1[j];
                Ah[j]     = h0;
                Ah[j + 4] = h1;
                Al[j]     = (_Float16)(x0[j] - (float)h0);
                Al[j + 4] = (_Float16)(x1[j] - (float)h1);
            }
#pragma unroll
            for (int t = 0; t < 7; ++t) {
                half8 Bh = wl[(s * 7 + t) * 64 + lane];
                half8 Bl = wl[1792 + (s * 7 + t) * 64 + lane];
                acc[t] = __builtin_amdgcn_mfma_f32_16x16x32_f16(Ah, Bh, acc[t], 0, 0, 0);
                acc[t] = __builtin_amdgcn_mfma_f32_16x16x32_f16(Al, Bh, acc[t], 0, 0, 0);
                acc[t] = __builtin_amdgcn_mfma_f32_16x16x32_f16(Ah, Bl, acc[t], 0, 0, 0);
            }
        }

        if (l < 7) {
            __syncthreads();   // all XT reads of layer l complete
            const int Nl = (l == 3) ? 98 : 100;
            const int cs = (l == 3) ? 2 : 0;
#pragma unroll
            for (int t = 0; t < 7; ++t) {
                int n = t * 16 + (lane & 15);
                float bv = (n < Nl) ? bp[n] : 0.0f;
#pragma unroll
                for (int i = 0; i < 4; ++i) {
                    float y = sp100(acc[t][i] + bv);
                    int row = wid * 16 + (lane >> 4) * 4 + i;
                    *reinterpret_cast<float*>(
                        reinterpret_cast<char*>(XT) + xtb(row, n + cs)) = y;
                }
            }
            if (l == 3 && tid < 2 * RPB) {   // skip-concat: inputs -> cols 0,1
                int row = tid >> 1, c = tid & 1;
                *reinterpret_cast<float*>(
                    reinterpret_cast<char*>(XT) + xtb(row, c)) = inps[row * 2 + c];
            }
            __syncthreads();
        } else {
            // ---- fused L8: dot with W8 over n, shuffle-reduce, store ----
            float p8[4] = {0.f, 0.f, 0.f, 0.f};
#pragma unroll
            for (int t = 0; t < 7; ++t) {
                int n = t * 16 + (lane & 15);
                float bv = (n < 100) ? bp[n] : 0.0f;
                float w8 = (n < 100) ? W8[n] : 0.0f;
#pragma unroll
                for (int i = 0; i < 4; ++i)
                    p8[i] = fmaf(w8, sp100(acc[t][i] + bv), p8[i]);
            }
            float b8v = b8[0];
#pragma unroll
            for (int i = 0; i < 4; ++i) {
                float v = p8[i];
                v += __shfl_xor(v, 1);
                v += __shfl_xor(v, 2);
                v += __shfl_xor(v, 4);
                v += __shfl_xor(v, 8);
                if ((lane & 15) == 0)
                    out[(size_t)bid * RPB + wid * 16 + (lane >> 4) * 4 + i] = v + b8v;
            }
        }
    }
}

// Pack W1..W7 ([out][in=100] fp32) -> per-layer [term(h/l)][s*7+t][lane] half8:
// half jj at k=32s+8*(lane>>4)+jj, n=16t+(lane&15);
// term0=(f16)W, term1=(f16)(W-(float)(f16)W). Zero outside K=100 / N=Nl.
__global__ void pack_weights(
    const float* __restrict__ W1, const float* __restrict__ W2,
    const float* __restrict__ W3, const float* __restrict__ W4,
    const float* __restrict__ W5, const float* __restrict__ W6,
    const float* __restrict__ W7, uint4* __restrict__ wpk)
{
    const float* Wt[7] = {W1, W2, W3, W4, W5, W6, W7};
    const float* W = Wt[blockIdx.x];
    const int Nl = (blockIdx.x == 2) ? 98 : 100;   // layer 3 outputs 98
    for (int e = threadIdx.x; e < 3584; e += 256) {
        int term = e / 1792;
        int r    = e - term * 1792;
        int lane = r & 63;
        int st   = r >> 6;
        int s    = st / 7;
        int t    = st - s * 7;
        union { _Float16 h[8]; uint4 v; } pk;
#pragma unroll
        for (int jj = 0; jj < 8; ++jj) {
            int k = s * 32 + (lane >> 4) * 8 + jj;
            int n = t * 16 + (lane & 15);
            float val = (k < 100 && n < Nl) ? W[n * 100 + k] : 0.0f;
            _Float16 h = (_Float16)val;
            pk.h[jj] = term ? (_Float16)(val - (float)h) : h;
        }
        wpk[blockIdx.x * 3584 + term * 1792 + r] = pk.v;
    }
}

extern "C" void kernel_launch(void* const* d_in, const int* in_sizes, int n_in,
                              void* d_out, int out_size, void* d_ws, size_t ws_size,
                              hipStream_t stream)
{
    const float* inp = (const float*)d_in[0];
    const float* W[9];
    const float* B[9];
    for (int l = 0; l < 9; ++l) {
        W[l] = (const float*)d_in[1 + 2 * l];
        B[l] = (const float*)d_in[2 + 2 * l];
    }
    uint4* wpk = (uint4*)d_ws;             // 7*3584*16 = 401,408 B
    float* out = (float*)d_out;
    const int N = in_sizes[0] / 2;         // 1,048,576 rows

    pack_weights<<<7, 256, 0, stream>>>(W[1], W[2], W[3], W[4], W[5], W[6], W[7], wpk);
    mlp_fwd<<<N / RPB, TPB, 0, stream>>>(inp, (const half8*)wpk,
                                         W[0], B[0],
                                         B[1], B[2], B[3], B[4], B[5], B[6], B[7],
                                         W[8], B[8],
                                         out);
}